// Round 9
// baseline (627.330 us; speedup 1.0000x reference)
//
#include <hip/hip_runtime.h>
#include <cstddef>

// Problem shape (fixed): N=50000, K=16, C_IN=128, C2=256, C_OUT=128.
#define C_IN  128
#define C2    256
#define C_OUT 128
#define KNBR  16

typedef unsigned short u16;
typedef __attribute__((ext_vector_type(8))) short bf16x8;   // 8 bf16 (4 VGPRs)
typedef __attribute__((ext_vector_type(4))) float f32x4;

__device__ __forceinline__ float bf2f(u16 h) {
    return __uint_as_float(((unsigned int)h) << 16);
}
__device__ __forceinline__ u16 f2bf(float x) {
    unsigned int u = __float_as_uint(x);
    return (u16)((u + 0x7fffu + ((u >> 16) & 1u)) >> 16);
}

// Transpose + convert weights to bf16, n-major [N][K].
__global__ void prep_k(const float* __restrict__ W1, const float* __restrict__ Ws,
                       const float* __restrict__ Wm, u16* __restrict__ W1t,
                       u16* __restrict__ Wst, u16* __restrict__ Wmt)
{
    const int n = blockIdx.x, t = threadIdx.x;
    if (blockIdx.y == 0) {
        if (t < 128) W1t[n * 128 + t] = f2bf(W1[t * 256 + n]);
    } else if (blockIdx.y == 1) {
        Wst[n * 256 + t] = f2bf(Ws[t * 256 + n]);
    } else {
        if (n < 128) Wmt[n * 256 + t] = f2bf(Wm[t * 128 + n]);
    }
}

// ---------------------------------------------------------------------------
// Weight-stationary barrier-free GEMMs: one 1024-thread block per CU, whole
// weight matrix resident in LDS (one barrier total), each wave independently
// processes 16-row tiles with A-frags straight from global in MFMA layout.
// MFMA 16x16x32 layouts (verified in R4-R8): A[m=lane&15][k=(lane>>4)*8+j],
// C col=lane&15, row=(lane>>4)*4+reg. Accumulators indexed only by unrolled
// vars (R7: runtime-indexed acc arrays spill to scratch).
// packed row (512 u16): [ey[0..255] | x[0..255]], both bf16.
// ---------------------------------------------------------------------------

// K1: x = BN(relu(F @ W1 + b1)) -> packed x-half.
__global__ __launch_bounds__(1024, 4)
void x_k(const float* __restrict__ F, const u16* __restrict__ W1t,
         const float* __restrict__ b1, const float* __restrict__ gamma,
         const float* __restrict__ beta, const float* __restrict__ mean,
         const float* __restrict__ var, u16* __restrict__ packed, int N)
{
    __shared__ u16 WL[256][136];            // 69.6 KB, 272 B row stride
    __shared__ float cb1[256], civ[256], cbb[256];
    const int tid = threadIdx.x;
    #pragma unroll
    for (int i = 0; i < 4; i++) {
        int idx = tid + i * 1024;
        int row = idx >> 4, g = (idx & 15) * 8;
        *(uint4*)&WL[row][g] = *(const uint4*)(W1t + (size_t)row * C_IN + g);
    }
    if (tid < 256) {
        float iv = gamma[tid] * rsqrtf(var[tid] + 1e-5f);
        civ[tid] = iv;
        cbb[tid] = beta[tid] - mean[tid] * iv;
        cb1[tid] = b1[tid];
    }
    __syncthreads();

    const int wv = tid >> 6, l = tid & 63, q = l >> 4, r = l & 15;
    const int ntiles = (N + 15) / 16;
    for (int t = blockIdx.x * 16 + wv; t < ntiles; t += gridDim.x * 16) {
        const int m0 = t * 16;
        const int arow = min(m0 + r, N - 1);
        f32x4 acc[16] = {};
        #pragma unroll
        for (int kk = 0; kk < 4; kk++) {
            float4 a0 = *(const float4*)(F + (size_t)arow * C_IN + kk * 32 + q * 8);
            float4 a1 = *(const float4*)(F + (size_t)arow * C_IN + kk * 32 + q * 8 + 4);
            bf16x8 af;
            af[0] = (short)f2bf(a0.x); af[1] = (short)f2bf(a0.y);
            af[2] = (short)f2bf(a0.z); af[3] = (short)f2bf(a0.w);
            af[4] = (short)f2bf(a1.x); af[5] = (short)f2bf(a1.y);
            af[6] = (short)f2bf(a1.z); af[7] = (short)f2bf(a1.w);
            #pragma unroll
            for (int n = 0; n < 16; n++) {
                bf16x8 bf = *(const bf16x8*)&WL[n * 16 + r][kk * 32 + q * 8];
                acc[n] = __builtin_amdgcn_mfma_f32_16x16x32_bf16(af, bf, acc[n], 0, 0, 0);
            }
        }
        #pragma unroll
        for (int n = 0; n < 16; n++) {
            const int ch = n * 16 + r;
            const float bi = cb1[ch], iv = civ[ch], bb = cbb[ch];
            #pragma unroll
            for (int p = 0; p < 4; p++) {
                const int m = m0 + q * 4 + p;
                if (m < N) {
                    float x = fmaxf(acc[n][p] + bi, 0.f);
                    packed[(size_t)m * 512 + 256 + ch] = f2bf(fmaf(x, iv, bb));
                }
            }
        }
    }
}

// K2: ey = exp(x @ Ws) -> packed ey-half (A = packed x-half, bf16).
__global__ __launch_bounds__(1024, 4)
void ey_k(const u16* __restrict__ packed_r, const u16* __restrict__ Wst,
          u16* __restrict__ packed_w, int N)
{
    __shared__ u16 WL[256][264];            // 135 KB, 528 B row stride
    const int tid = threadIdx.x;
    #pragma unroll
    for (int i = 0; i < 8; i++) {
        int idx = tid + i * 1024;
        int row = idx >> 5, g = (idx & 31) * 8;
        *(uint4*)&WL[row][g] = *(const uint4*)(Wst + (size_t)row * C2 + g);
    }
    __syncthreads();

    const int wv = tid >> 6, l = tid & 63, q = l >> 4, r = l & 15;
    const int ntiles = (N + 15) / 16;
    for (int t = blockIdx.x * 16 + wv; t < ntiles; t += gridDim.x * 16) {
        const int m0 = t * 16;
        const int arow = min(m0 + r, N - 1);
        f32x4 acc[16] = {};
        #pragma unroll
        for (int kk = 0; kk < 8; kk++) {
            bf16x8 af = *(const bf16x8*)(packed_r + (size_t)arow * 512 + 256
                                         + kk * 32 + q * 8);
            #pragma unroll
            for (int n = 0; n < 16; n++) {
                bf16x8 bf = *(const bf16x8*)&WL[n * 16 + r][kk * 32 + q * 8];
                acc[n] = __builtin_amdgcn_mfma_f32_16x16x32_bf16(af, bf, acc[n], 0, 0, 0);
            }
        }
        #pragma unroll
        for (int n = 0; n < 16; n++) {
            const int ch = n * 16 + r;
            #pragma unroll
            for (int p = 0; p < 4; p++) {
                const int m = m0 + q * 4 + p;
                if (m < N)
                    packed_w[(size_t)m * 512 + ch] = f2bf(__expf(acc[n][p]));
            }
        }
    }
}

// K3b: out = featb @ Wm + bm.  featb aliases out (same 512 B/row footprint);
// each wave reads its own 16 rows fully before writing them -> safe. No
// __restrict__ on the aliasing pointers.
__global__ __launch_bounds__(1024, 4)
void out_k(const u16* featb, const u16* __restrict__ Wmt,
           const float* __restrict__ bm, float* out, int N)
{
    __shared__ u16 WL[128][264];            // 67.6 KB
    __shared__ float cbm[128];
    const int tid = threadIdx.x;
    #pragma unroll
    for (int i = 0; i < 4; i++) {
        int idx = tid + i * 1024;
        int row = idx >> 5, g = (idx & 31) * 8;
        *(uint4*)&WL[row][g] = *(const uint4*)(Wmt + (size_t)row * C2 + g);
    }
    if (tid < 128) cbm[tid] = bm[tid];
    __syncthreads();

    const int wv = tid >> 6, l = tid & 63, q = l >> 4, r = l & 15;
    const int ntiles = (N + 15) / 16;
    for (int t = blockIdx.x * 16 + wv; t < ntiles; t += gridDim.x * 16) {
        const int m0 = t * 16;
        const int arow = min(m0 + r, N - 1);
        f32x4 acc[8] = {};
        #pragma unroll
        for (int kk = 0; kk < 8; kk++) {
            bf16x8 af = *(const bf16x8*)(featb + (size_t)arow * C2 + kk * 32 + q * 8);
            #pragma unroll
            for (int n = 0; n < 8; n++) {
                bf16x8 bf = *(const bf16x8*)&WL[n * 16 + r][kk * 32 + q * 8];
                acc[n] = __builtin_amdgcn_mfma_f32_16x16x32_bf16(af, bf, acc[n], 0, 0, 0);
            }
        }
        #pragma unroll
        for (int n = 0; n < 8; n++) {
            const int ch = n * 16 + r;
            const float bo = cbm[ch];
            #pragma unroll
            for (int p = 0; p < 4; p++) {
                const int m = m0 + q * 4 + p;
                if (m < N) out[(size_t)m * C_OUT + ch] = acc[n][p] + bo;
            }
        }
    }
}

// One wave per point: gather 16 packed rows ([ey|x] halves), 32 8B loads,
// pool = (sum ey*x)/(sum ey) per channel, write bf16 feat.
__global__ __launch_bounds__(256)
void gather_k(const u16* __restrict__ packed, const int* __restrict__ nidx,
              u16* __restrict__ featb, int N)
{
    __shared__ int rows[4 * KNBR];
    const int tid = threadIdx.x;
    const int p0 = blockIdx.x * 4;

    if (tid < 4 * KNBR) {
        int n = p0 + (tid >> 4);
        rows[tid] = (n < N) ? nidx[n * KNBR + (tid & 15)] : 0;
    }
    __syncthreads();

    const int w = tid >> 6;       // wave id -> point p0+w
    const int l = tid & 63;       // channels 4l..4l+3
    const int p = p0 + w;
    if (p >= N) return;

    ushort4 eh[KNBR], xh[KNBR];
    #pragma unroll
    for (int k = 0; k < KNBR; k++) {
        const size_t base = (size_t)rows[w * KNBR + k] * 512;
        eh[k] = *(const ushort4*)(packed + base + l * 4);
        xh[k] = *(const ushort4*)(packed + base + 256 + l * 4);
    }

    float d0 = 0.f, d1 = 0.f, d2 = 0.f, d3 = 0.f;
    float u0 = 0.f, u1 = 0.f, u2 = 0.f, u3 = 0.f;
    #pragma unroll
    for (int k = 0; k < KNBR; k++) {
        float e0 = bf2f(eh[k].x), e1 = bf2f(eh[k].y);
        float e2 = bf2f(eh[k].z), e3 = bf2f(eh[k].w);
        d0 += e0; d1 += e1; d2 += e2; d3 += e3;
        u0 = fmaf(e0, bf2f(xh[k].x), u0);
        u1 = fmaf(e1, bf2f(xh[k].y), u1);
        u2 = fmaf(e2, bf2f(xh[k].z), u2);
        u3 = fmaf(e3, bf2f(xh[k].w), u3);
    }
    ushort4 o;
    o.x = f2bf(u0 / d0); o.y = f2bf(u1 / d1);
    o.z = f2bf(u2 / d2); o.w = f2bf(u3 / d3);
    *(ushort4*)(featb + (size_t)p * C2 + l * 4) = o;
}

extern "C" void kernel_launch(void* const* d_in, const int* in_sizes, int n_in,
                              void* d_out, int out_size, void* d_ws, size_t ws_size,
                              hipStream_t stream)
{
    const float* features = (const float*)d_in[0];
    const int*   nidx     = (const int*)d_in[1];
    const float* W1       = (const float*)d_in[2];
    const float* b1       = (const float*)d_in[3];
    const float* gamma    = (const float*)d_in[4];
    const float* beta     = (const float*)d_in[5];
    const float* mean     = (const float*)d_in[6];
    const float* var      = (const float*)d_in[7];
    const float* Ws       = (const float*)d_in[8];
    const float* Wm       = (const float*)d_in[9];
    const float* bm       = (const float*)d_in[10];
    float* out = (float*)d_out;

    const int N = in_sizes[0] / C_IN;   // 50000

    u16* packed = (u16*)d_ws;                      // N x 512 ([ey|x] bf16)
    u16* W1t    = packed + (size_t)N * 512;        // 256 x 128
    u16* Wst    = W1t + 256 * 128;                 // 256 x 256
    u16* Wmt    = Wst + 256 * 256;                 // 128 x 256
    // feat lives in d_out: bf16 N x 256 (512 B/row) == out fp32 N x 128
    // (512 B/row). out_k waves read their own rows fully before writing.
    u16* featb = (u16*)d_out;

    prep_k<<<dim3(256, 3), 256, 0, stream>>>(W1, Ws, Wm, W1t, Wst, Wmt);

    x_k<<<256, 1024, 0, stream>>>(features, W1t, b1, gamma, beta, mean, var,
                                  packed, N);
    ey_k<<<256, 1024, 0, stream>>>(packed, Wst, packed, N);
    gather_k<<<(N + 3) / 4, 256, 0, stream>>>(packed, nidx, featb, N);
    out_k<<<256, 1024, 0, stream>>>(featb, Wmt, bm, out, N);
}

// Round 10
// 420.775 us; speedup vs baseline: 1.4909x; 1.4909x over previous
//
#include <hip/hip_runtime.h>
#include <cstddef>

// Problem shape (fixed): N=50000, K=16, C_IN=128, C2=256, C_OUT=128.
#define C_IN  128
#define C2    256
#define C_OUT 128
#define KNBR  16

typedef unsigned short u16;
typedef __attribute__((ext_vector_type(8))) short bf16x8;   // 8 bf16 (4 VGPRs)
typedef __attribute__((ext_vector_type(4))) float f32x4;

__device__ __forceinline__ float bf2f(u16 h) {
    return __uint_as_float(((unsigned int)h) << 16);
}
__device__ __forceinline__ u16 f2bf(float x) {
    unsigned int u = __float_as_uint(x);
    return (u16)((u + 0x7fffu + ((u >> 16) & 1u)) >> 16);
}

// Transpose + convert weights to bf16, n-major [N][K].
__global__ void prep_k(const float* __restrict__ W1, const float* __restrict__ Ws,
                       const float* __restrict__ Wm, u16* __restrict__ W1t,
                       u16* __restrict__ Wst, u16* __restrict__ Wmt)
{
    const int n = blockIdx.x, t = threadIdx.x;
    if (blockIdx.y == 0) {
        if (t < 128) W1t[n * 128 + t] = f2bf(W1[t * 256 + n]);
    } else if (blockIdx.y == 1) {
        Wst[n * 256 + t] = f2bf(Ws[t * 256 + n]);
    } else {
        if (n < 128) Wmt[n * 256 + t] = f2bf(Wm[t * 128 + n]);
    }
}

// ---------------------------------------------------------------------------
// Weight-stationary barrier-free GEMMs (R9 main loop, verified): 1024-thread
// blocks, whole weight matrix in LDS (one barrier total), each wave owns
// 16-row tiles, A-frags straight from global in MFMA layout.
// R9 LESSON: scattered sub-dword global stores cause write-allocate RMW
// (WRITE_SIZE 410 MB for 26 MB logical). ALL epilogues now stage into a
// wave-private LDS tile (132-elem row pad: 2-way bank alias only, 8B-aligned)
// and flush with coalesced uint2/float2 stores. No barriers needed.
// R7 LESSON: accumulators indexed only by fully-unrolled loop vars.
// packed row (512 u16): [ey[0..255] | x[0..255]], both bf16.
// ---------------------------------------------------------------------------

// K1: x = BN(relu(F @ W1 + b1)) -> packed x-half.
__global__ __launch_bounds__(1024, 4)
void x_k(const float* __restrict__ F, const u16* __restrict__ W1t,
         const float* __restrict__ b1, const float* __restrict__ gamma,
         const float* __restrict__ beta, const float* __restrict__ mean,
         const float* __restrict__ var, u16* __restrict__ packed, int N)
{
    __shared__ u16 WL[256][136];        // 69.6 KB
    __shared__ u16 ST[16][16][132];     // 67.6 KB wave-private staging
    __shared__ float cb1[256], civ[256], cbb[256];
    const int tid = threadIdx.x;
    #pragma unroll
    for (int i = 0; i < 4; i++) {
        int idx = tid + i * 1024;
        int row = idx >> 4, g = (idx & 15) * 8;
        *(uint4*)&WL[row][g] = *(const uint4*)(W1t + (size_t)row * C_IN + g);
    }
    if (tid < 256) {
        float iv = gamma[tid] * rsqrtf(var[tid] + 1e-5f);
        civ[tid] = iv;
        cbb[tid] = beta[tid] - mean[tid] * iv;
        cb1[tid] = b1[tid];
    }
    __syncthreads();

    const int wv = tid >> 6, l = tid & 63, q = l >> 4, r = l & 15;
    const int ntiles = (N + 15) / 16;
    for (int t = blockIdx.x * 16 + wv; t < ntiles; t += gridDim.x * 16) {
        const int m0 = t * 16;
        const int arow = min(m0 + r, N - 1);
        f32x4 acc[16] = {};
        #pragma unroll
        for (int kk = 0; kk < 4; kk++) {
            float4 a0 = *(const float4*)(F + (size_t)arow * C_IN + kk * 32 + q * 8);
            float4 a1 = *(const float4*)(F + (size_t)arow * C_IN + kk * 32 + q * 8 + 4);
            bf16x8 af;
            af[0] = (short)f2bf(a0.x); af[1] = (short)f2bf(a0.y);
            af[2] = (short)f2bf(a0.z); af[3] = (short)f2bf(a0.w);
            af[4] = (short)f2bf(a1.x); af[5] = (short)f2bf(a1.y);
            af[6] = (short)f2bf(a1.z); af[7] = (short)f2bf(a1.w);
            #pragma unroll
            for (int n = 0; n < 16; n++) {
                bf16x8 bf = *(const bf16x8*)&WL[n * 16 + r][kk * 32 + q * 8];
                acc[n] = __builtin_amdgcn_mfma_f32_16x16x32_bf16(af, bf, acc[n], 0, 0, 0);
            }
        }
        // epilogue in two 128-ch halves: stage -> coalesced flush
        #pragma unroll
        for (int hh = 0; hh < 2; hh++) {
            #pragma unroll
            for (int n = 0; n < 8; n++) {
                const int chl = n * 16 + r;
                const int ch = hh * 128 + chl;
                const float bi = cb1[ch], iv = civ[ch], bb = cbb[ch];
                #pragma unroll
                for (int p = 0; p < 4; p++) {
                    float x = fmaxf(acc[hh * 8 + n][p] + bi, 0.f);
                    ST[wv][q * 4 + p][chl] = f2bf(fmaf(x, iv, bb));
                }
            }
            #pragma unroll
            for (int i = 0; i < 8; i++) {
                int fi = i * 64 + l;
                int row = fi >> 5, c8 = fi & 31;    // 32 uint2 per 256B row-half
                int m = m0 + row;
                if (m < N)
                    *(uint2*)(packed + (size_t)m * 512 + 256 + hh * 128 + c8 * 4) =
                        *(const uint2*)&ST[wv][row][c8 * 4];
            }
        }
    }
}

// K2: ey = exp(x @ Ws) -> packed ey-half. blockIdx.y picks 128-ch half.
__global__ __launch_bounds__(1024, 4)
void ey_k(const u16* __restrict__ packed_r, const u16* __restrict__ Wst,
          u16* __restrict__ packed_w, int N)
{
    __shared__ u16 WL[128][264];        // 67.6 KB (this half's weights)
    __shared__ u16 ST[16][16][132];     // 67.6 KB
    const int tid = threadIdx.x;
    const int hy = blockIdx.y;
    #pragma unroll
    for (int i = 0; i < 4; i++) {
        int idx = tid + i * 1024;
        int row = idx >> 5, g = (idx & 31) * 8;
        *(uint4*)&WL[row][g] =
            *(const uint4*)(Wst + (size_t)(hy * 128 + row) * C2 + g);
    }
    __syncthreads();

    const int wv = tid >> 6, l = tid & 63, q = l >> 4, r = l & 15;
    const int ntiles = (N + 15) / 16;
    for (int t = blockIdx.x * 16 + wv; t < ntiles; t += gridDim.x * 16) {
        const int m0 = t * 16;
        const int arow = min(m0 + r, N - 1);
        f32x4 acc[8] = {};
        #pragma unroll
        for (int kk = 0; kk < 8; kk++) {
            bf16x8 af = *(const bf16x8*)(packed_r + (size_t)arow * 512 + 256
                                         + kk * 32 + q * 8);
            #pragma unroll
            for (int n = 0; n < 8; n++) {
                bf16x8 bf = *(const bf16x8*)&WL[n * 16 + r][kk * 32 + q * 8];
                acc[n] = __builtin_amdgcn_mfma_f32_16x16x32_bf16(af, bf, acc[n], 0, 0, 0);
            }
        }
        #pragma unroll
        for (int n = 0; n < 8; n++) {
            const int chl = n * 16 + r;
            #pragma unroll
            for (int p = 0; p < 4; p++)
                ST[wv][q * 4 + p][chl] = f2bf(__expf(acc[n][p]));
        }
        #pragma unroll
        for (int i = 0; i < 8; i++) {
            int fi = i * 64 + l;
            int row = fi >> 5, c8 = fi & 31;
            int m = m0 + row;
            if (m < N)
                *(uint2*)(packed_w + (size_t)m * 512 + hy * 128 + c8 * 4) =
                    *(const uint2*)&ST[wv][row][c8 * 4];
        }
    }
}

// K3b: out = featb @ Wm + bm. featb aliases out (same 512 B/row footprint);
// each wave reads its own 16 rows fully before writing them -> safe.
__global__ __launch_bounds__(1024, 4)
void out_k(const u16* featb, const u16* __restrict__ Wmt,
           const float* __restrict__ bm, float* out, int N)
{
    __shared__ u16 WL[128][264];        // 67.6 KB
    __shared__ float STF[16][16][66];   // 67.6 KB (fp32 staging, half-width)
    __shared__ float cbm[128];
    const int tid = threadIdx.x;
    #pragma unroll
    for (int i = 0; i < 4; i++) {
        int idx = tid + i * 1024;
        int row = idx >> 5, g = (idx & 31) * 8;
        *(uint4*)&WL[row][g] = *(const uint4*)(Wmt + (size_t)row * C2 + g);
    }
    if (tid < 128) cbm[tid] = bm[tid];
    __syncthreads();

    const int wv = tid >> 6, l = tid & 63, q = l >> 4, r = l & 15;
    const int ntiles = (N + 15) / 16;
    for (int t = blockIdx.x * 16 + wv; t < ntiles; t += gridDim.x * 16) {
        const int m0 = t * 16;
        const int arow = min(m0 + r, N - 1);
        f32x4 acc[8] = {};
        #pragma unroll
        for (int kk = 0; kk < 8; kk++) {
            bf16x8 af = *(const bf16x8*)(featb + (size_t)arow * C2 + kk * 32 + q * 8);
            #pragma unroll
            for (int n = 0; n < 8; n++) {
                bf16x8 bf = *(const bf16x8*)&WL[n * 16 + r][kk * 32 + q * 8];
                acc[n] = __builtin_amdgcn_mfma_f32_16x16x32_bf16(af, bf, acc[n], 0, 0, 0);
            }
        }
        // two 64-ch halves: stage fp32 -> coalesced float2 flush
        #pragma unroll
        for (int hh = 0; hh < 2; hh++) {
            #pragma unroll
            for (int n = 0; n < 4; n++) {
                const int chl = n * 16 + r;             // 0..63
                const int ch = hh * 64 + chl;
                const float bo = cbm[ch];
                #pragma unroll
                for (int p = 0; p < 4; p++)
                    STF[wv][q * 4 + p][chl] = acc[hh * 4 + n][p] + bo;
            }
            #pragma unroll
            for (int i = 0; i < 8; i++) {
                int fi = i * 64 + l;
                int row = fi >> 5, c2 = fi & 31;    // 32 float2 per 256B half
                int m = m0 + row;
                if (m < N)
                    *(float2*)(out + (size_t)m * C_OUT + hh * 64 + c2 * 2) =
                        *(const float2*)&STF[wv][row][c2 * 2];
            }
        }
    }
}

// One wave per point: gather 16 packed rows ([ey|x] halves), 32 8B loads,
// pool = (sum ey*x)/(sum ey) per channel, write bf16 feat.
__global__ __launch_bounds__(256)
void gather_k(const u16* __restrict__ packed, const int* __restrict__ nidx,
              u16* __restrict__ featb, int N)
{
    __shared__ int rows[4 * KNBR];
    const int tid = threadIdx.x;
    const int p0 = blockIdx.x * 4;

    if (tid < 4 * KNBR) {
        int n = p0 + (tid >> 4);
        rows[tid] = (n < N) ? nidx[n * KNBR + (tid & 15)] : 0;
    }
    __syncthreads();

    const int w = tid >> 6;       // wave id -> point p0+w
    const int l = tid & 63;       // channels 4l..4l+3
    const int p = p0 + w;
    if (p >= N) return;

    ushort4 eh[KNBR], xh[KNBR];
    #pragma unroll
    for (int k = 0; k < KNBR; k++) {
        const size_t base = (size_t)rows[w * KNBR + k] * 512;
        eh[k] = *(const ushort4*)(packed + base + l * 4);
        xh[k] = *(const ushort4*)(packed + base + 256 + l * 4);
    }

    float d0 = 0.f, d1 = 0.f, d2 = 0.f, d3 = 0.f;
    float u0 = 0.f, u1 = 0.f, u2 = 0.f, u3 = 0.f;
    #pragma unroll
    for (int k = 0; k < KNBR; k++) {
        float e0 = bf2f(eh[k].x), e1 = bf2f(eh[k].y);
        float e2 = bf2f(eh[k].z), e3 = bf2f(eh[k].w);
        d0 += e0; d1 += e1; d2 += e2; d3 += e3;
        u0 = fmaf(e0, bf2f(xh[k].x), u0);
        u1 = fmaf(e1, bf2f(xh[k].y), u1);
        u2 = fmaf(e2, bf2f(xh[k].z), u2);
        u3 = fmaf(e3, bf2f(xh[k].w), u3);
    }
    ushort4 o;
    o.x = f2bf(u0 / d0); o.y = f2bf(u1 / d1);
    o.z = f2bf(u2 / d2); o.w = f2bf(u3 / d3);
    *(ushort4*)(featb + (size_t)p * C2 + l * 4) = o;
}

extern "C" void kernel_launch(void* const* d_in, const int* in_sizes, int n_in,
                              void* d_out, int out_size, void* d_ws, size_t ws_size,
                              hipStream_t stream)
{
    const float* features = (const float*)d_in[0];
    const int*   nidx     = (const int*)d_in[1];
    const float* W1       = (const float*)d_in[2];
    const float* b1       = (const float*)d_in[3];
    const float* gamma    = (const float*)d_in[4];
    const float* beta     = (const float*)d_in[5];
    const float* mean     = (const float*)d_in[6];
    const float* var      = (const float*)d_in[7];
    const float* Ws       = (const float*)d_in[8];
    const float* Wm       = (const float*)d_in[9];
    const float* bm       = (const float*)d_in[10];
    float* out = (float*)d_out;

    const int N = in_sizes[0] / C_IN;   // 50000

    u16* packed = (u16*)d_ws;                      // N x 512 ([ey|x] bf16)
    u16* W1t    = packed + (size_t)N * 512;        // 256 x 128
    u16* Wst    = W1t + 256 * 128;                 // 256 x 256
    u16* Wmt    = Wst + 256 * 256;                 // 128 x 256
    // feat lives in d_out: bf16 N x 256 (512 B/row) == out fp32 N x 128
    // (512 B/row). out_k waves read their own rows fully before writing.
    u16* featb = (u16*)d_out;

    prep_k<<<dim3(256, 3), 256, 0, stream>>>(W1, Ws, Wm, W1t, Wst, Wmt);

    x_k<<<256, 1024, 0, stream>>>(features, W1t, b1, gamma, beta, mean, var,
                                  packed, N);
    ey_k<<<dim3(128, 2), 1024, 0, stream>>>(packed, Wst, packed, N);
    gather_k<<<(N + 3) / 4, 256, 0, stream>>>(packed, nidx, featb, N);
    out_k<<<256, 1024, 0, stream>>>(featb, Wmt, bm, out, N);
}

// Round 11
// 250.734 us; speedup vs baseline: 2.5020x; 1.6782x over previous
//
#include <hip/hip_runtime.h>
#include <cstddef>

// Problem shape (fixed): N=50000, K=16, C_IN=128, C2=256, C_OUT=128.
#define C_IN  128
#define C2    256
#define C_OUT 128
#define KNBR  16

typedef unsigned short u16;
typedef __attribute__((ext_vector_type(8))) short bf16x8;   // 8 bf16 (4 VGPRs)
typedef __attribute__((ext_vector_type(4))) float f32x4;

__device__ __forceinline__ float bf2f(u16 h) {
    return __uint_as_float(((unsigned int)h) << 16);
}
__device__ __forceinline__ u16 f2bf(float x) {
    unsigned int u = __float_as_uint(x);
    return (u16)((u + 0x7fffu + ((u >> 16) & 1u)) >> 16);
}

// Transpose + convert weights to bf16, n-major [N][K].
__global__ void prep_k(const float* __restrict__ W1, const float* __restrict__ Ws,
                       const float* __restrict__ Wm, u16* __restrict__ W1t,
                       u16* __restrict__ Wst, u16* __restrict__ Wmt)
{
    const int n = blockIdx.x, t = threadIdx.x;
    if (blockIdx.y == 0) {
        if (t < 128) W1t[n * 128 + t] = f2bf(W1[t * 256 + n]);
    } else if (blockIdx.y == 1) {
        Wst[n * 256 + t] = f2bf(Ws[t * 256 + n]);
    } else {
        if (n < 128) Wmt[n * 256 + t] = f2bf(Wm[t * 128 + n]);
    }
}

// ---------------------------------------------------------------------------
// LESSONS ENCODED:
//  R7: accumulator arrays indexed by non-unrolled loop vars spill to scratch.
//  R9: scattered sub-dword global stores -> write-allocate RMW (16x bytes).
//  R10: 1-block/CU weight-stationary waves have zero latency hiding.
// This round: R8's proven barrier-tiled GEMM bodies, shrunk to 64-row tiles
// so LDS <= 80 KB -> 2 blocks/CU -> cross-block overlap of barrier drains.
// packed row (512 u16): [ey[0..255] | x[0..255]], both bf16.
// ---------------------------------------------------------------------------

// Fused MLP, 64-row blocks (69.6 KB LDS -> 2 blocks/CU):
//   x  = BN(relu(F @ W1 + b1))  -> xs (LDS) -> coalesced flush to packed
//   ey = exp(x @ Ws)            -> As reuse -> coalesced flush to packed
__global__ __launch_bounds__(256)
void mlp_k(const float* __restrict__ F, const u16* __restrict__ W1t,
           const u16* __restrict__ Wst,
           const float* __restrict__ bias, const float* __restrict__ gamma,
           const float* __restrict__ beta, const float* __restrict__ mean,
           const float* __restrict__ var,
           u16* __restrict__ packed, int N)
{
    __shared__ u16 As[64][136];    // features tile (GEMM1); ey staging (epi 2)
    __shared__ u16 Bs[128][72];    // weight k-slice staging
    __shared__ u16 xs[64][264];    // x tile, full K=256

    const int tid = threadIdx.x;
    const int w = tid >> 6, l = tid & 63, q = l >> 4, r = l & 15;
    const int wm = w & 1, wn = w >> 1;
    const int m0 = blockIdx.x * 64;

    // stage As: 64 x 128 fp32 -> bf16 (2048 float4, 8/thread)
    #pragma unroll
    for (int i = 0; i < 8; i++) {
        int idx = tid + i * 256;
        int row = idx >> 5, c4 = (idx & 31) * 4;
        int gm = m0 + row;
        float4 v = make_float4(0.f, 0.f, 0.f, 0.f);
        if (gm < N) v = *(const float4*)(F + (size_t)gm * C_IN + c4);
        ushort4 h;
        h.x = f2bf(v.x); h.y = f2bf(v.y); h.z = f2bf(v.z); h.w = f2bf(v.w);
        *(ushort4*)&As[row][c4] = h;
    }

    // ---- GEMM1: x = F @ W1, two 128-col halves (nh fully unrolled) ----
    #pragma unroll
    for (int nh = 0; nh < 2; nh++) {
        f32x4 acc[2][4] = {};
        #pragma unroll 1
        for (int k0 = 0; k0 < C_IN; k0 += 64) {
            __syncthreads();   // prior Bs readers done (also covers As stage)
            #pragma unroll
            for (int i = 0; i < 4; i++) {
                int idx = tid + i * 256;
                int row = idx >> 3, g = (idx & 7) * 8;
                *(uint4*)&Bs[row][g] = *(const uint4*)(
                    W1t + (size_t)(nh * 128 + row) * C_IN + k0 + g);
            }
            __syncthreads();
            #pragma unroll
            for (int h = 0; h < 2; h++) {
                bf16x8 af[2], bfr[4];
                #pragma unroll
                for (int i = 0; i < 2; i++)
                    af[i] = *(const bf16x8*)&As[wm * 32 + i * 16 + r][k0 + h * 32 + q * 8];
                #pragma unroll
                for (int j = 0; j < 4; j++)
                    bfr[j] = *(const bf16x8*)&Bs[wn * 64 + j * 16 + r][h * 32 + q * 8];
                #pragma unroll
                for (int i = 0; i < 2; i++)
                    #pragma unroll
                    for (int j = 0; j < 4; j++)
                        acc[i][j] = __builtin_amdgcn_mfma_f32_16x16x32_bf16(
                            af[i], bfr[j], acc[i][j], 0, 0, 0);
            }
        }
        // epilogue 1: BN(relu(z+bias)) -> xs (LDS only)
        #pragma unroll
        for (int j = 0; j < 4; j++) {
            const int ch = nh * 128 + wn * 64 + j * 16 + r;
            const float bi = bias[ch], be = beta[ch], mu = mean[ch];
            const float iv = gamma[ch] * rsqrtf(var[ch] + 1e-5f);
            #pragma unroll
            for (int i = 0; i < 2; i++) {
                const int mb = wm * 32 + i * 16 + q * 4;
                #pragma unroll
                for (int p = 0; p < 4; p++) {
                    float x = fmaxf(acc[i][j][p] + bi, 0.f);
                    x = (x - mu) * iv + be;
                    xs[mb + p][ch] = f2bf(x);
                }
            }
        }
    }
    __syncthreads();   // xs complete (cross-wave)
    // coalesced flush: x-half of packed (64 x 256 u16 = 2048 uint4, 8/thread)
    #pragma unroll
    for (int i = 0; i < 8; i++) {
        int idx = tid + i * 256;
        int row = idx >> 5, g = (idx & 31) * 8;
        if (m0 + row < N)
            *(uint4*)(packed + (size_t)(m0 + row) * 512 + 256 + g) =
                *(const uint4*)&xs[row][g];
    }

    // ---- GEMM2: ey = exp(x @ Ws), A from xs (nh fully unrolled) ----
    #pragma unroll
    for (int nh = 0; nh < 2; nh++) {
        f32x4 acc[2][4] = {};
        #pragma unroll 1
        for (int k0 = 0; k0 < C2; k0 += 64) {
            __syncthreads();   // prior Bs readers / xs-flush / As-flush done
            #pragma unroll
            for (int i = 0; i < 4; i++) {
                int idx = tid + i * 256;
                int row = idx >> 3, g = (idx & 7) * 8;
                *(uint4*)&Bs[row][g] = *(const uint4*)(
                    Wst + (size_t)(nh * 128 + row) * C2 + k0 + g);
            }
            __syncthreads();
            #pragma unroll
            for (int h = 0; h < 2; h++) {
                bf16x8 af[2], bfr[4];
                #pragma unroll
                for (int i = 0; i < 2; i++)
                    af[i] = *(const bf16x8*)&xs[wm * 32 + i * 16 + r][k0 + h * 32 + q * 8];
                #pragma unroll
                for (int j = 0; j < 4; j++)
                    bfr[j] = *(const bf16x8*)&Bs[wn * 64 + j * 16 + r][h * 32 + q * 8];
                #pragma unroll
                for (int i = 0; i < 2; i++)
                    #pragma unroll
                    for (int j = 0; j < 4; j++)
                        acc[i][j] = __builtin_amdgcn_mfma_f32_16x16x32_bf16(
                            af[i], bfr[j], acc[i][j], 0, 0, 0);
            }
        }
        // epilogue 2: ey -> As reuse (cols local to this nh-half)
        __syncthreads();       // prior As flush-readers done
        #pragma unroll
        for (int j = 0; j < 4; j++) {
            const int chl = wn * 64 + j * 16 + r;   // 0..127 within half
            #pragma unroll
            for (int i = 0; i < 2; i++) {
                const int mb = wm * 32 + i * 16 + q * 4;
                #pragma unroll
                for (int p = 0; p < 4; p++)
                    As[mb + p][chl] = f2bf(__expf(acc[i][j][p]));
            }
        }
        __syncthreads();       // As (ey half) complete
        // coalesced flush: ey nh-half (64 x 128 u16 = 1024 uint4, 4/thread)
        #pragma unroll
        for (int i = 0; i < 4; i++) {
            int idx = tid + i * 256;
            int row = idx >> 4, g = (idx & 15) * 8;
            if (m0 + row < N)
                *(uint4*)(packed + (size_t)(m0 + row) * 512 + nh * 128 + g) =
                    *(const uint4*)&As[row][g];
        }
    }
}

// Output GEMM, 64-row blocks (59 KB LDS -> 2 blocks/CU):
// out = featb @ Wm + bm. featb aliases out (both 512 B/row); a block reads
// all its A rows before writing them, rows are block-private -> safe.
__global__ __launch_bounds__(256)
void out_gemm(const u16* A, const u16* __restrict__ Bt,
              const float* __restrict__ bias, float* Cf, int N)
{
    __shared__ u16 As[64][72];         //  9.2 KB
    __shared__ u16 Bs[128][72];        // 18.4 KB
    __shared__ float STF[64][132];     // 33.8 KB fp32 epilogue staging
    const int tid = threadIdx.x;
    const int w = tid >> 6, l = tid & 63, q = l >> 4, r = l & 15;
    const int wm = w & 1, wn = w >> 1;
    const int m0 = blockIdx.x * 64;

    f32x4 acc[2][4] = {};

    #pragma unroll 1
    for (int k0 = 0; k0 < C2; k0 += 64) {
        __syncthreads();
        #pragma unroll
        for (int i = 0; i < 2; i++) {      // As: 64x64 u16 = 512 uint4
            int idx = tid + i * 256;
            int row = idx >> 3, g = (idx & 7) * 8;
            int gm = m0 + row;
            uint4 v = make_uint4(0u, 0u, 0u, 0u);
            if (gm < N) v = *(const uint4*)(A + (size_t)gm * C2 + k0 + g);
            *(uint4*)&As[row][g] = v;
        }
        #pragma unroll
        for (int i = 0; i < 4; i++) {      // Bs: 128x64 u16 = 1024 uint4
            int idx = tid + i * 256;
            int row = idx >> 3, g = (idx & 7) * 8;
            *(uint4*)&Bs[row][g] = *(const uint4*)(
                Bt + (size_t)row * C2 + k0 + g);   // Wmt is 128 x 256
        }
        __syncthreads();
        #pragma unroll
        for (int h = 0; h < 2; h++) {
            bf16x8 af[2], bfr[4];
            #pragma unroll
            for (int i = 0; i < 2; i++)
                af[i] = *(const bf16x8*)&As[wm * 32 + i * 16 + r][h * 32 + q * 8];
            #pragma unroll
            for (int j = 0; j < 4; j++)
                bfr[j] = *(const bf16x8*)&Bs[wn * 64 + j * 16 + r][h * 32 + q * 8];
            #pragma unroll
            for (int i = 0; i < 2; i++)
                #pragma unroll
                for (int j = 0; j < 4; j++)
                    acc[i][j] = __builtin_amdgcn_mfma_f32_16x16x32_bf16(
                        af[i], bfr[j], acc[i][j], 0, 0, 0);
        }
    }
    __syncthreads();

    // epilogue: stage fp32 tile in LDS, then full-line float4 flush (R9 lesson)
    #pragma unroll
    for (int j = 0; j < 4; j++) {
        const int ch = wn * 64 + j * 16 + r;
        const float bo = bias[ch];
        #pragma unroll
        for (int i = 0; i < 2; i++) {
            const int mb = wm * 32 + i * 16 + q * 4;
            #pragma unroll
            for (int p = 0; p < 4; p++)
                STF[mb + p][ch] = acc[i][j][p] + bo;
        }
    }
    __syncthreads();
    #pragma unroll
    for (int i = 0; i < 8; i++) {          // 64x128 fp32 = 2048 float4
        int idx = tid + i * 256;
        int row = idx >> 5, c4 = (idx & 31) * 4;
        if (m0 + row < N)
            *(float4*)(Cf + (size_t)(m0 + row) * C_OUT + c4) =
                *(const float4*)&STF[row][c4];
    }
}

// One wave per point: gather 16 packed rows ([ey|x] halves), 32 8B loads,
// pool = (sum ey*x)/(sum ey) per channel, write bf16 feat.
__global__ __launch_bounds__(256)
void gather_k(const u16* __restrict__ packed, const int* __restrict__ nidx,
              u16* __restrict__ featb, int N)
{
    __shared__ int rows[4 * KNBR];
    const int tid = threadIdx.x;
    const int p0 = blockIdx.x * 4;

    if (tid < 4 * KNBR) {
        int n = p0 + (tid >> 4);
        rows[tid] = (n < N) ? nidx[n * KNBR + (tid & 15)] : 0;
    }
    __syncthreads();

    const int w = tid >> 6;       // wave id -> point p0+w
    const int l = tid & 63;       // channels 4l..4l+3
    const int p = p0 + w;
    if (p >= N) return;

    ushort4 eh[KNBR], xh[KNBR];
    #pragma unroll
    for (int k = 0; k < KNBR; k++) {
        const size_t base = (size_t)rows[w * KNBR + k] * 512;
        eh[k] = *(const ushort4*)(packed + base + l * 4);
        xh[k] = *(const ushort4*)(packed + base + 256 + l * 4);
    }

    float d0 = 0.f, d1 = 0.f, d2 = 0.f, d3 = 0.f;
    float u0 = 0.f, u1 = 0.f, u2 = 0.f, u3 = 0.f;
    #pragma unroll
    for (int k = 0; k < KNBR; k++) {
        float e0 = bf2f(eh[k].x), e1 = bf2f(eh[k].y);
        float e2 = bf2f(eh[k].z), e3 = bf2f(eh[k].w);
        d0 += e0; d1 += e1; d2 += e2; d3 += e3;
        u0 = fmaf(e0, bf2f(xh[k].x), u0);
        u1 = fmaf(e1, bf2f(xh[k].y), u1);
        u2 = fmaf(e2, bf2f(xh[k].z), u2);
        u3 = fmaf(e3, bf2f(xh[k].w), u3);
    }
    ushort4 o;
    o.x = f2bf(u0 / d0); o.y = f2bf(u1 / d1);
    o.z = f2bf(u2 / d2); o.w = f2bf(u3 / d3);
    *(ushort4*)(featb + (size_t)p * C2 + l * 4) = o;
}

extern "C" void kernel_launch(void* const* d_in, const int* in_sizes, int n_in,
                              void* d_out, int out_size, void* d_ws, size_t ws_size,
                              hipStream_t stream)
{
    const float* features = (const float*)d_in[0];
    const int*   nidx     = (const int*)d_in[1];
    const float* W1       = (const float*)d_in[2];
    const float* b1       = (const float*)d_in[3];
    const float* gamma    = (const float*)d_in[4];
    const float* beta     = (const float*)d_in[5];
    const float* mean     = (const float*)d_in[6];
    const float* var      = (const float*)d_in[7];
    const float* Ws       = (const float*)d_in[8];
    const float* Wm       = (const float*)d_in[9];
    const float* bm       = (const float*)d_in[10];
    float* out = (float*)d_out;

    const int N = in_sizes[0] / C_IN;   // 50000

    u16* packed = (u16*)d_ws;                      // N x 512 ([ey|x] bf16)
    u16* W1t    = packed + (size_t)N * 512;        // 256 x 128
    u16* Wst    = W1t + 256 * 128;                 // 256 x 256
    u16* Wmt    = Wst + 256 * 256;                 // 128 x 256
    // feat lives in d_out: bf16 N x 256 (512 B/row) == out fp32 N x 128
    // (512 B/row). out_gemm blocks read their own rows before writing.
    u16* featb = (u16*)d_out;

    prep_k<<<dim3(256, 3), 256, 0, stream>>>(W1, Ws, Wm, W1t, Wst, Wmt);

    const int MT = (N + 63) / 64;   // 782

    mlp_k<<<MT, 256, 0, stream>>>(features, W1t, Wst, b1, gamma, beta,
                                  mean, var, packed, N);
    gather_k<<<(N + 3) / 4, 256, 0, stream>>>(packed, nidx, featb, N);
    out_gemm<<<MT, 256, 0, stream>>>(featb, Wmt, bm, out, N);
}